// Round 16
// baseline (206.461 us; speedup 1.0000x reference)
//
#include <hip/hip_runtime.h>
#include <hip/hip_bf16.h>

#define D 64
#define EPS 1e-8f
#define BSH 8                          // nodes per bucket = 256
#define BNODES (1 << BSH)
#define ABLK 8192                      // edges per bucketA block
#define AUNR 32                        // ABLK / 256

typedef __attribute__((ext_vector_type(8))) short bf16x8;
typedef __attribute__((ext_vector_type(4))) float f32x4;
typedef unsigned long long ull;

__device__ __forceinline__ unsigned short f2bf_rn(float f) {
    unsigned u = __float_as_uint(f);
    return (unsigned short)((u + 0x7FFFu + ((u >> 16) & 1u)) >> 16);
}

__device__ __forceinline__ void split8(float4 a, float4 b, bf16x8& h, bf16x8& l) {
    float f[8] = {a.x, a.y, a.z, a.w, b.x, b.y, b.z, b.w};
    #pragma unroll
    for (int i = 0; i < 8; ++i) {
        unsigned u = __float_as_uint(f[i]);
        float hf = __uint_as_float(u & 0xFFFF0000u);
        unsigned lu = __float_as_uint(f[i] - hf);
        h[i] = (short)(u >> 16);
        l[i] = (short)(lu >> 16);
    }
}

// ================= device bodies =================

// embed: 16 lanes/node, 4 nodes/wave, 16 nodes/block(256)
__device__ __forceinline__ void embed_body(int bid, const float* __restrict__ x,
                                           float* __restrict__ P, int n) {
    int lane = threadIdx.x & 63, wv = threadIdx.x >> 6;
    int q = lane >> 4, sub = lane & 15;
    int node = bid * 16 + wv * 4 + q;
    if (node >= n) return;
    const float* xr = x + (size_t)node * 63;
    float v0 = 0.f, v1, v2, v3;
    if (sub == 0) {
        v1 = xr[0]; v2 = xr[1]; v3 = xr[2];
    } else {
        int b = sub * 4 - 1;
        v0 = xr[b]; v1 = xr[b + 1]; v2 = xr[b + 2]; v3 = xr[b + 3];
    }
    float s = v0 * v0 + v1 * v1 + v2 * v2 + v3 * v3;
    #pragma unroll
    for (int d2 = 1; d2 < 16; d2 <<= 1) s += __shfl_xor(s, d2);
    float nrm = fmaxf(sqrtf(s), EPS);
    float sh = sinhf(nrm);
    float k = sh / nrm;
    float4 r;
    if (sub == 0) r = make_float4(sqrtf(1.f + sh * sh), k * v1, k * v2, k * v3);
    else          r = make_float4(k * v0, k * v1, k * v2, k * v3);
    *(float4*)(P + (size_t)node * 64 + sub * 4) = r;
}

// per-bucket edge counts (LDS-aggregated); 1024 edges/block
__device__ __forceinline__ void bcount_body(int bid, const int* __restrict__ dst,
                                            int* __restrict__ bcnt, int e, int nbuck) {
    __shared__ int cnt[320];
    int tid = threadIdx.x;
    for (int b = tid; b < nbuck; b += 256) cnt[b] = 0;
    __syncthreads();
    int i0 = bid * 1024 + tid;
    #pragma unroll
    for (int u = 0; u < 4; ++u) {
        int i = i0 + u * 256;
        if (i < e) atomicAdd(&cnt[dst[i] >> BSH], 1);
    }
    __syncthreads();
    for (int b = tid; b < nbuck; b += 256)
        if (cnt[b]) atomicAdd(&bcnt[b], cnt[b]);
}

// bucketA: bucket edges by dst>>BSH; pack [w:32][dstlow:8 @20][src:20]
__device__ __forceinline__ void bucketA_body(int bid, const int* __restrict__ src,
                                             const int* __restrict__ dst,
                                             const float* __restrict__ w,
                                             int* __restrict__ gcur,
                                             ull* __restrict__ tmp,
                                             int e, int nbuck) {
    __shared__ int cnt[320];
    __shared__ int base[320];
    int tid = threadIdx.x;
    for (int b = tid; b < nbuck; b += 256) cnt[b] = 0;
    __syncthreads();
    int i0 = bid * ABLK + tid;
    int bkt[AUNR], rnk[AUNR];
    #pragma unroll
    for (int u = 0; u < AUNR; ++u) {
        int i = i0 + u * 256;
        if (i < e) {
            int b = dst[i] >> BSH;
            bkt[u] = b;
            rnk[u] = atomicAdd(&cnt[b], 1);
        }
    }
    __syncthreads();
    for (int b = tid; b < nbuck; b += 256) {
        int c = cnt[b];
        base[b] = c ? atomicAdd(&gcur[b], c) : 0;
    }
    __syncthreads();
    #pragma unroll
    for (int u = 0; u < AUNR; ++u) {
        int i = i0 + u * 256;
        if (i < e) {
            ull pk = ((ull)__float_as_uint(w[i]) << 32)
                   | (unsigned)(src[i] | ((dst[i] & (BNODES - 1)) << 20));
            tmp[base[bkt[u]] + rnk[u]] = pk;
        }
    }
}

// Lorentz linear via split-bf16 MFMA; bf16 output table. 64 nodes/block.
template <int RELU>
__device__ __forceinline__ void lin_body(int bid, const float* __restrict__ tbl,
                                         const float* __restrict__ W,
                                         const float* __restrict__ bias,
                                         const float* __restrict__ sc,
                                         unsigned short* __restrict__ out, int n) {
    int lane = threadIdx.x & 63, wv = threadIdx.x >> 6;
    int col = lane & 15, grp = lane >> 4;
    int node0 = bid * 64 + wv * 16;
    if (node0 >= n) return;

    float es = expf(sc[0]);

    bf16x8 wh[2][4], wl[2][4];
    #pragma unroll
    for (int s = 0; s < 2; ++s)
        #pragma unroll
        for (int t = 0; t < 4; ++t) {
            const float* wp = W + (t * 16 + col) * 64 + s * 32 + grp * 8;
            split8(*(const float4*)wp, *(const float4*)(wp + 4), wh[s][t], wl[s][t]);
        }

    f32x4 acc[4];
    #pragma unroll
    for (int t = 0; t < 4; ++t) {
        float bv = bias[t * 16 + col];
        acc[t] = (f32x4){bv, bv, bv, bv};
    }

    int arow = node0 + col;
    if (arow >= n) arow = n - 1;
    #pragma unroll
    for (int s = 0; s < 2; ++s) {
        const float* ap = tbl + (size_t)arow * 64 + s * 32 + grp * 8;
        float4 a0 = *(const float4*)ap;
        float4 a1 = *(const float4*)(ap + 4);
        if (RELU) {
            a0.x = fmaxf(a0.x, 0.f); a0.y = fmaxf(a0.y, 0.f);
            a0.z = fmaxf(a0.z, 0.f); a0.w = fmaxf(a0.w, 0.f);
            a1.x = fmaxf(a1.x, 0.f); a1.y = fmaxf(a1.y, 0.f);
            a1.z = fmaxf(a1.z, 0.f); a1.w = fmaxf(a1.w, 0.f);
        }
        bf16x8 ah, al;
        split8(a0, a1, ah, al);
        #pragma unroll
        for (int t = 0; t < 4; ++t) {
            acc[t] = __builtin_amdgcn_mfma_f32_16x16x32_bf16(ah, wh[s][t], acc[t], 0, 0, 0);
            acc[t] = __builtin_amdgcn_mfma_f32_16x16x32_bf16(al, wh[s][t], acc[t], 0, 0, 0);
            acc[t] = __builtin_amdgcn_mfma_f32_16x16x32_bf16(ah, wl[s][t], acc[t], 0, 0, 0);
        }
    }

    float tot[4];
    #pragma unroll
    for (int r = 0; r < 4; ++r) {
        float s = 0.f;
        #pragma unroll
        for (int t = 0; t < 4; ++t) s += acc[t][r] * acc[t][r];
        tot[r] = s;
    }
    #pragma unroll
    for (int d2 = 1; d2 < 16; d2 <<= 1) {
        #pragma unroll
        for (int r = 0; r < 4; ++r) tot[r] += __shfl_xor(tot[r], d2);
    }
    float tm[4], rs[4];
    #pragma unroll
    for (int r = 0; r < 4; ++r) {
        float h0 = __shfl(acc[0][r], lane & 48);
        tm[r] = es / (1.f + expf(-h0)) + 1.1f;
        float sq = fmaxf(tot[r] - h0 * h0, EPS);
        rs[r] = sqrtf((tm[r] * tm[r] - 1.f) / sq);
    }
    #pragma unroll
    for (int t = 0; t < 4; ++t) {
        #pragma unroll
        for (int r = 0; r < 4; ++r) {
            int row = node0 + grp * 4 + r;
            if (row < n) {
                int j = t * 16 + col;
                float v = (j == 0) ? tm[r] : acc[t][r] * rs[r];
                out[(size_t)row * 64 + j] = f2bf_rn(v);
            }
        }
    }
}

// ================= kernels =================

// F1: embed and bcount blocks INTERLEAVED (Bresenham) for true overlap.
__global__ __launch_bounds__(256) void k_f1(const float* __restrict__ x,
                                            float* __restrict__ P,
                                            const int* __restrict__ dst,
                                            int* __restrict__ bcnt,
                                            int n, int e, int nbuck,
                                            int gEm, int gB) {
    int bid = blockIdx.x;
    int total = gEm + gB;
    int a = (int)(((long long)bid * gB) / total);
    int b = (int)(((long long)(bid + 1) * gB) / total);
    if (b > a) bcount_body(a, dst, bcnt, e, nbuck);
    else       embed_body(bid - a, x, P, n);
}

// scan bucket counts -> bstart[0..nbuck], gcur copy, off[n]=e
__global__ __launch_bounds__(512) void k_bscan(const int* __restrict__ bcnt,
                                               int* __restrict__ bstart,
                                               int* __restrict__ gcur,
                                               int* __restrict__ off,
                                               int n, int e, int nbuck) {
    __shared__ int sm[512];
    int tid = threadIdx.x;
    int v = (tid < nbuck) ? bcnt[tid] : 0;
    sm[tid] = v;
    __syncthreads();
    #pragma unroll
    for (int d = 1; d < 512; d <<= 1) {
        int t = (tid >= d) ? sm[tid - d] : 0;
        __syncthreads();
        sm[tid] += t;
        __syncthreads();
    }
    int excl = sm[tid] - v;
    if (tid < nbuck) { bstart[tid] = excl; gcur[tid] = excl; }
    if (tid == 0) { bstart[nbuck] = e; off[n] = e; }
}

// F2: bucketA (blocks [0,nA)) || lin1 (blocks [nA, nA+gL))
__global__ __launch_bounds__(256) void k_f2(const int* __restrict__ src,
                                            const int* __restrict__ dst,
                                            const float* __restrict__ wE,
                                            int* __restrict__ gcur,
                                            ull* __restrict__ tmp,
                                            int e, int nbuck, int nA,
                                            const float* __restrict__ P,
                                            const float* __restrict__ W1,
                                            const float* __restrict__ b1,
                                            const float* __restrict__ s1,
                                            unsigned short* __restrict__ T, int n) {
    if ((int)blockIdx.x < nA) bucketA_body(blockIdx.x, src, dst, wE, gcur, tmp, e, nbuck);
    else                      lin_body<0>(blockIdx.x - nA, P, W1, b1, s1, T, n);
}

// Pass B: per bucket: LDS node-hist + scan -> off, then scatter
__global__ __launch_bounds__(1024) void k_bucketB(const ull* __restrict__ tmp,
                                                  const int* __restrict__ bstart,
                                                  int* __restrict__ off,
                                                  ull* __restrict__ epack,
                                                  int n) {
    __shared__ int cur[BNODES];
    __shared__ int sm[BNODES];
    int b = blockIdx.x;
    int v0 = b << BSH;
    int nv = min(BNODES, n - v0);
    int tid = threadIdx.x;
    if (tid < BNODES) cur[tid] = 0;
    __syncthreads();
    int s0 = bstart[b], s1 = bstart[b + 1];
    for (int i = s0 + tid; i < s1; i += 1024)
        atomicAdd(&cur[((unsigned)tmp[i] >> 20) & (BNODES - 1)], 1);
    __syncthreads();
    int v = 0;
    if (tid < BNODES) { v = cur[tid]; sm[tid] = v; }
    __syncthreads();
    #pragma unroll
    for (int d = 1; d < BNODES; d <<= 1) {
        int t = 0;
        if (tid < BNODES && tid >= d) t = sm[tid - d];
        __syncthreads();
        if (tid < BNODES) sm[tid] += t;
        __syncthreads();
    }
    if (tid < BNODES) {
        int node_off = s0 + sm[tid] - v;
        if (tid < nv) off[v0 + tid] = node_off;
        cur[tid] = node_off;
    }
    __syncthreads();
    for (int i = s0 + tid; i < s1; i += 1024) {
        ull pk = tmp[i];
        int dl = ((unsigned)pk >> 20) & (BNODES - 1);
        int pos = atomicAdd(&cur[dl], 1);
        epack[pos] = pk;
    }
}

// ---- agg layer-1 FUSED with lin2: 16 nodes/block (4 waves x 4 nodes),
// stage relu(h1) in LDS, wave-0 MFMA epilogue writes T2.
__global__ __launch_bounds__(256, 6) void k_aggF(const unsigned short* __restrict__ t,
                                                 const int* __restrict__ off,
                                                 const ull* __restrict__ epack,
                                                 const float* __restrict__ W2,
                                                 const float* __restrict__ b2,
                                                 const float* __restrict__ s2,
                                                 float* __restrict__ h1,
                                                 unsigned short* __restrict__ T2,
                                                 int n) {
    __shared__ __align__(16) ull ebuf[4][64];
    __shared__ float hbuf[16][65];              // +1 pad: MFMA A-read banks
    int tid = threadIdx.x;
    int lane = tid & 63, wv = tid >> 6;
    int q = lane >> 4, sub = lane & 15;
    int nb0 = blockIdx.x * 16;

    #pragma unroll 1
    for (int k = 0; k < 4; ++k) {
        int node = nb0 + wv * 4 + k;
        int ln = wv * 4 + k;
        float hx = 0.f, hy = 0.f, hz = 0.f, hw = 0.f;
        if (node < n) {
            int s0 = off[node], s1 = off[node + 1];
            float ax = 0.f, ay = 0.f, az = 0.f, aw = 0.f;
            for (int base = s0; base < s1; base += 64) {
                int c = min(s1 - base, 64);
                ull ev = 0;
                if (lane < c) ev = __builtin_nontemporal_load(&epack[base + lane]);
                ebuf[wv][lane] = ev;            // same-wave LDS ordering
                int c4 = (c + 3) & ~3;
                for (int j = 0; j < c4; j += 4) {
                    ull e = ebuf[wv][j + q];
                    float w = __uint_as_float((unsigned)(e >> 32));
                    unsigned srcn = (unsigned)e & 0xFFFFFu;
                    uint2 rv = *(const uint2*)((const unsigned*)(t + ((size_t)srcn << 6)) + sub * 2);
                    ax += w * __uint_as_float(rv.x << 16);
                    ay += w * __uint_as_float(rv.x & 0xFFFF0000u);
                    az += w * __uint_as_float(rv.y << 16);
                    aw += w * __uint_as_float(rv.y & 0xFFFF0000u);
                }
            }
            #pragma unroll
            for (int d2 = 16; d2 <= 32; d2 <<= 1) {
                ax += __shfl_xor(ax, d2);
                ay += __shfl_xor(ay, d2);
                az += __shfl_xor(az, d2);
                aw += __shfl_xor(aw, d2);
            }
            float s = ay * ay + az * az + aw * aw;
            s += (sub == 0) ? -ax * ax : ax * ax;
            #pragma unroll
            for (int d2 = 1; d2 < 16; d2 <<= 1) s += __shfl_xor(s, d2);
            float inv = 1.f / sqrtf(fmaxf(fabsf(s), EPS));
            hx = ax * inv; hy = ay * inv; hz = az * inv; hw = aw * inv;
            if (lane < 16)
                *(float4*)(h1 + (size_t)node * 64 + sub * 4) = make_float4(hx, hy, hz, hw);
        }
        if (lane < 16) {
            hbuf[ln][sub * 4 + 0] = fmaxf(hx, 0.f);
            hbuf[ln][sub * 4 + 1] = fmaxf(hy, 0.f);
            hbuf[ln][sub * 4 + 2] = fmaxf(hz, 0.f);
            hbuf[ln][sub * 4 + 3] = fmaxf(hw, 0.f);
        }
    }
    __syncthreads();

    if (wv == 0 && nb0 < n) {
        int col = lane & 15, grp = lane >> 4;
        float es = expf(s2[0]);
        bf16x8 wh[2][4], wl[2][4];
        #pragma unroll
        for (int s = 0; s < 2; ++s)
            #pragma unroll
            for (int tt = 0; tt < 4; ++tt) {
                const float* wp = W2 + (tt * 16 + col) * 64 + s * 32 + grp * 8;
                split8(*(const float4*)wp, *(const float4*)(wp + 4), wh[s][tt], wl[s][tt]);
            }
        f32x4 accd[4];
        #pragma unroll
        for (int tt = 0; tt < 4; ++tt) {
            float bv = b2[tt * 16 + col];
            accd[tt] = (f32x4){bv, bv, bv, bv};
        }
        #pragma unroll
        for (int s = 0; s < 2; ++s) {
            float a8[8];
            #pragma unroll
            for (int j = 0; j < 8; ++j) a8[j] = hbuf[col][s * 32 + grp * 8 + j];
            bf16x8 ah, al;
            split8(make_float4(a8[0], a8[1], a8[2], a8[3]),
                   make_float4(a8[4], a8[5], a8[6], a8[7]), ah, al);
            #pragma unroll
            for (int tt = 0; tt < 4; ++tt) {
                accd[tt] = __builtin_amdgcn_mfma_f32_16x16x32_bf16(ah, wh[s][tt], accd[tt], 0, 0, 0);
                accd[tt] = __builtin_amdgcn_mfma_f32_16x16x32_bf16(al, wh[s][tt], accd[tt], 0, 0, 0);
                accd[tt] = __builtin_amdgcn_mfma_f32_16x16x32_bf16(ah, wl[s][tt], accd[tt], 0, 0, 0);
            }
        }
        float tot[4];
        #pragma unroll
        for (int r = 0; r < 4; ++r) {
            float s = 0.f;
            #pragma unroll
            for (int tt = 0; tt < 4; ++tt) s += accd[tt][r] * accd[tt][r];
            tot[r] = s;
        }
        #pragma unroll
        for (int d2 = 1; d2 < 16; d2 <<= 1) {
            #pragma unroll
            for (int r = 0; r < 4; ++r) tot[r] += __shfl_xor(tot[r], d2);
        }
        float tm[4], rs[4];
        #pragma unroll
        for (int r = 0; r < 4; ++r) {
            float h0 = __shfl(accd[0][r], lane & 48);
            tm[r] = es / (1.f + expf(-h0)) + 1.1f;
            float sq = fmaxf(tot[r] - h0 * h0, EPS);
            rs[r] = sqrtf((tm[r] * tm[r] - 1.f) / sq);
        }
        #pragma unroll
        for (int tt = 0; tt < 4; ++tt) {
            #pragma unroll
            for (int r = 0; r < 4; ++r) {
                int row = nb0 + grp * 4 + r;
                if (row < n) {
                    int j = tt * 16 + col;
                    float v = (j == 0) ? tm[r] : accd[tt][r] * rs[r];
                    T2[(size_t)row * 64 + j] = f2bf_rn(v);
                }
            }
        }
    }
}

// ---- agg layer-2 (unchanged from R15): 4 nodes/block -----------------------
__global__ __launch_bounds__(256) void k_agg2(const unsigned short* __restrict__ t,
                                              const int* __restrict__ off,
                                              const ull* __restrict__ epack,
                                              const float* __restrict__ h1,
                                              float* __restrict__ out, int n) {
    __shared__ __align__(16) ull ebuf[4][64];
    int lane = threadIdx.x & 63, wv = threadIdx.x >> 6;
    int q = lane >> 4, sub = lane & 15;
    int node = blockIdx.x * 4 + wv;
    if (node >= n) return;
    int s0 = off[node], s1 = off[node + 1];
    float ax = 0.f, ay = 0.f, az = 0.f, aw = 0.f;
    for (int base = s0; base < s1; base += 64) {
        int c = min(s1 - base, 64);
        ull ev = 0;
        if (lane < c) ev = __builtin_nontemporal_load(&epack[base + lane]);
        ebuf[wv][lane] = ev;
        int ng = (c + 3) >> 2;
        uint2 rv[16]; float wgt[16];
        #pragma unroll
        for (int g = 0; g < 16; ++g) {
            if (g < ng) {
                ull e = ebuf[wv][g * 4 + q];
                wgt[g] = __uint_as_float((unsigned)(e >> 32));
                unsigned srcn = (unsigned)e & 0xFFFFFu;
                rv[g] = *(const uint2*)((const unsigned*)(t + ((size_t)srcn << 6)) + sub * 2);
            }
        }
        #pragma unroll
        for (int g = 0; g < 16; ++g) {
            if (g < ng) {
                float w = wgt[g];
                ax += w * __uint_as_float(rv[g].x << 16);
                ay += w * __uint_as_float(rv[g].x & 0xFFFF0000u);
                az += w * __uint_as_float(rv[g].y << 16);
                aw += w * __uint_as_float(rv[g].y & 0xFFFF0000u);
            }
        }
    }
    #pragma unroll
    for (int d2 = 16; d2 <= 32; d2 <<= 1) {
        ax += __shfl_xor(ax, d2);
        ay += __shfl_xor(ay, d2);
        az += __shfl_xor(az, d2);
        aw += __shfl_xor(aw, d2);
    }
    float s = ay * ay + az * az + aw * aw;
    s += (sub == 0) ? -ax * ax : ax * ax;
    #pragma unroll
    for (int d2 = 1; d2 < 16; d2 <<= 1) s += __shfl_xor(s, d2);
    float inv = 1.f / sqrtf(fmaxf(fabsf(s), EPS));
    float hx = ax * inv, hy = ay * inv, hz = az * inv, hw = aw * inv;
    f32x4 hv = __builtin_nontemporal_load(
        (const f32x4*)(h1 + (size_t)node * 64 + sub * 4));
    float vx = hv[0] + hx, vy = hv[1] + hy, vz = hv[2] + hz, vw = hv[3] + hw;
    float s2 = vy * vy + vz * vz + vw * vw;
    s2 += (sub == 0) ? -vx * vx : vx * vx;
    #pragma unroll
    for (int d2 = 1; d2 < 16; d2 <<= 1) s2 += __shfl_xor(s2, d2);
    float inv2 = 1.f / sqrtf(fmaxf(fabsf(s2), EPS));
    if (lane < 16) {
        float4 r = make_float4(vx * inv2, vy * inv2, vz * inv2, vw * inv2);
        *(float4*)(out + (size_t)node * 64 + sub * 4) = r;
    }
}

extern "C" void kernel_launch(void* const* d_in, const int* in_sizes, int n_in,
                              void* d_out, int out_size, void* d_ws, size_t ws_size,
                              hipStream_t stream) {
    const float* x  = (const float*)d_in[0];
    const int*   ei = (const int*)d_in[1];
    const float* wE = (const float*)d_in[2];
    const float* W1 = (const float*)d_in[3];
    const float* b1 = (const float*)d_in[4];
    const float* s1 = (const float*)d_in[5];
    const float* W2 = (const float*)d_in[6];
    const float* b2 = (const float*)d_in[7];
    const float* s2 = (const float*)d_in[8];
    float* out = (float*)d_out;

    const int N = in_sizes[0] / (D - 1);
    const int E = in_sizes[2];
    const int* src = ei;
    const int* dst = ei + E;
    const int nbuck = (N + BNODES - 1) >> BSH;         // 313

    // Regions: T (bf16 tables T1/T2 share: T1 consumed by aggF before T2 write?
    //   NO - aggF reads T1 while writing T2 -> keep DISTINCT)
    char* ws = (char*)d_ws;
    size_t szT = (((size_t)N * D * 2) + 255) & ~(size_t)255;
    unsigned short* T1 = (unsigned short*)ws;
    unsigned short* T2 = (unsigned short*)(ws + szT);
    float* B2 = (float*)(ws + 2 * szT);                // f32 P, then h1
    ull* epack = (ull*)((char*)B2 + (size_t)N * D * 4);
    ull* tmp   = epack + E;
    int* off    = (int*)(tmp + E);                     // N+1
    int* bcnt   = off + (N + 1);                       // 320
    int* bstart = bcnt + 320;                          // 320
    int* gcur   = bstart + 320;                        // 320

    hipMemsetAsync(bcnt, 0, 320 * sizeof(int), stream);

    int gE4 = (E + 1023) / 1024;                       // 1250
    int gEm = (N + 15) / 16;                           // 5000
    int nA  = (E + ABLK - 1) / ABLK;                   // 157
    int gL  = (N + 63) / 64;                           // 1250
    int gAF = (N + 15) / 16;                           // 5000
    int gA2 = (N + 3) / 4;                             // 20000

    k_f1<<<gEm + gE4, 256, 0, stream>>>(x, B2, dst, bcnt, N, E, nbuck, gEm, gE4);
    k_bscan<<<1, 512, 0, stream>>>(bcnt, bstart, gcur, off, N, E, nbuck);
    k_f2<<<nA + gL, 256, 0, stream>>>(src, dst, wE, gcur, tmp, E, nbuck, nA,
                                      B2, W1, b1, s1, T1, N);
    k_bucketB<<<nbuck, 1024, 0, stream>>>(tmp, bstart, off, epack, N);

    k_aggF<<<gAF, 256, 0, stream>>>(T1, off, epack, W2, b2, s2, B2, T2, N);
    k_agg2<<<gA2, 256, 0, stream>>>(T2, off, epack, B2, out, N);
}

// Round 17
// 195.370 us; speedup vs baseline: 1.0568x; 1.0568x over previous
//
#include <hip/hip_runtime.h>
#include <hip/hip_bf16.h>

#define D 64
#define EPS 1e-8f
#define BSH 8                          // nodes per bucket = 256
#define BNODES (1 << BSH)
#define ABLK 8192                      // edges per bucketA block
#define AUNR 32                        // ABLK / 256

typedef __attribute__((ext_vector_type(8))) short bf16x8;
typedef __attribute__((ext_vector_type(4))) float f32x4;
typedef unsigned long long ull;

__device__ __forceinline__ unsigned short f2bf_rn(float f) {
    unsigned u = __float_as_uint(f);
    return (unsigned short)((u + 0x7FFFu + ((u >> 16) & 1u)) >> 16);
}

__device__ __forceinline__ void split8(float4 a, float4 b, bf16x8& h, bf16x8& l) {
    float f[8] = {a.x, a.y, a.z, a.w, b.x, b.y, b.z, b.w};
    #pragma unroll
    for (int i = 0; i < 8; ++i) {
        unsigned u = __float_as_uint(f[i]);
        float hf = __uint_as_float(u & 0xFFFF0000u);
        unsigned lu = __float_as_uint(f[i] - hf);
        h[i] = (short)(u >> 16);
        l[i] = (short)(lu >> 16);
    }
}

// ================= device bodies =================

// embed: 16 lanes/node, 4 nodes/wave, 16 nodes/block(256)
__device__ __forceinline__ void embed_body(int bid, const float* __restrict__ x,
                                           float* __restrict__ P, int n) {
    int lane = threadIdx.x & 63, wv = threadIdx.x >> 6;
    int q = lane >> 4, sub = lane & 15;
    int node = bid * 16 + wv * 4 + q;
    if (node >= n) return;
    const float* xr = x + (size_t)node * 63;
    float v0 = 0.f, v1, v2, v3;
    if (sub == 0) {
        v1 = xr[0]; v2 = xr[1]; v3 = xr[2];
    } else {
        int b = sub * 4 - 1;
        v0 = xr[b]; v1 = xr[b + 1]; v2 = xr[b + 2]; v3 = xr[b + 3];
    }
    float s = v0 * v0 + v1 * v1 + v2 * v2 + v3 * v3;
    #pragma unroll
    for (int d2 = 1; d2 < 16; d2 <<= 1) s += __shfl_xor(s, d2);
    float nrm = fmaxf(sqrtf(s), EPS);
    float sh = sinhf(nrm);
    float k = sh / nrm;
    float4 r;
    if (sub == 0) r = make_float4(sqrtf(1.f + sh * sh), k * v1, k * v2, k * v3);
    else          r = make_float4(k * v0, k * v1, k * v2, k * v3);
    *(float4*)(P + (size_t)node * 64 + sub * 4) = r;
}

// per-bucket edge counts (LDS-aggregated); 1024 edges/block
__device__ __forceinline__ void bcount_body(int bid, const int* __restrict__ dst,
                                            int* __restrict__ bcnt, int e, int nbuck) {
    __shared__ int cnt[320];
    int tid = threadIdx.x;
    for (int b = tid; b < nbuck; b += 256) cnt[b] = 0;
    __syncthreads();
    int i0 = bid * 1024 + tid;
    #pragma unroll
    for (int u = 0; u < 4; ++u) {
        int i = i0 + u * 256;
        if (i < e) atomicAdd(&cnt[dst[i] >> BSH], 1);
    }
    __syncthreads();
    for (int b = tid; b < nbuck; b += 256)
        if (cnt[b]) atomicAdd(&bcnt[b], cnt[b]);
}

// bucketA: bucket edges by dst>>BSH; pack [w:32][dstlow:8 @20][src:20]
__device__ __forceinline__ void bucketA_body(int bid, const int* __restrict__ src,
                                             const int* __restrict__ dst,
                                             const float* __restrict__ w,
                                             int* __restrict__ gcur,
                                             ull* __restrict__ tmp,
                                             int e, int nbuck) {
    __shared__ int cnt[320];
    __shared__ int base[320];
    int tid = threadIdx.x;
    for (int b = tid; b < nbuck; b += 256) cnt[b] = 0;
    __syncthreads();
    int i0 = bid * ABLK + tid;
    int bkt[AUNR], rnk[AUNR];
    #pragma unroll
    for (int u = 0; u < AUNR; ++u) {
        int i = i0 + u * 256;
        if (i < e) {
            int b = dst[i] >> BSH;
            bkt[u] = b;
            rnk[u] = atomicAdd(&cnt[b], 1);
        }
    }
    __syncthreads();
    for (int b = tid; b < nbuck; b += 256) {
        int c = cnt[b];
        base[b] = c ? atomicAdd(&gcur[b], c) : 0;
    }
    __syncthreads();
    #pragma unroll
    for (int u = 0; u < AUNR; ++u) {
        int i = i0 + u * 256;
        if (i < e) {
            ull pk = ((ull)__float_as_uint(w[i]) << 32)
                   | (unsigned)(src[i] | ((dst[i] & (BNODES - 1)) << 20));
            tmp[base[bkt[u]] + rnk[u]] = pk;
        }
    }
}

// Lorentz linear via split-bf16 MFMA; bf16 output table. 64 nodes/block.
template <int RELU>
__device__ __forceinline__ void lin_body(int bid, const float* __restrict__ tbl,
                                         const float* __restrict__ W,
                                         const float* __restrict__ bias,
                                         const float* __restrict__ sc,
                                         unsigned short* __restrict__ out, int n) {
    int lane = threadIdx.x & 63, wv = threadIdx.x >> 6;
    int col = lane & 15, grp = lane >> 4;
    int node0 = bid * 64 + wv * 16;
    if (node0 >= n) return;

    float es = expf(sc[0]);

    bf16x8 wh[2][4], wl[2][4];
    #pragma unroll
    for (int s = 0; s < 2; ++s)
        #pragma unroll
        for (int t = 0; t < 4; ++t) {
            const float* wp = W + (t * 16 + col) * 64 + s * 32 + grp * 8;
            split8(*(const float4*)wp, *(const float4*)(wp + 4), wh[s][t], wl[s][t]);
        }

    f32x4 acc[4];
    #pragma unroll
    for (int t = 0; t < 4; ++t) {
        float bv = bias[t * 16 + col];
        acc[t] = (f32x4){bv, bv, bv, bv};
    }

    int arow = node0 + col;
    if (arow >= n) arow = n - 1;
    #pragma unroll
    for (int s = 0; s < 2; ++s) {
        const float* ap = tbl + (size_t)arow * 64 + s * 32 + grp * 8;
        float4 a0 = *(const float4*)ap;
        float4 a1 = *(const float4*)(ap + 4);
        if (RELU) {
            a0.x = fmaxf(a0.x, 0.f); a0.y = fmaxf(a0.y, 0.f);
            a0.z = fmaxf(a0.z, 0.f); a0.w = fmaxf(a0.w, 0.f);
            a1.x = fmaxf(a1.x, 0.f); a1.y = fmaxf(a1.y, 0.f);
            a1.z = fmaxf(a1.z, 0.f); a1.w = fmaxf(a1.w, 0.f);
        }
        bf16x8 ah, al;
        split8(a0, a1, ah, al);
        #pragma unroll
        for (int t = 0; t < 4; ++t) {
            acc[t] = __builtin_amdgcn_mfma_f32_16x16x32_bf16(ah, wh[s][t], acc[t], 0, 0, 0);
            acc[t] = __builtin_amdgcn_mfma_f32_16x16x32_bf16(al, wh[s][t], acc[t], 0, 0, 0);
            acc[t] = __builtin_amdgcn_mfma_f32_16x16x32_bf16(ah, wl[s][t], acc[t], 0, 0, 0);
        }
    }

    float tot[4];
    #pragma unroll
    for (int r = 0; r < 4; ++r) {
        float s = 0.f;
        #pragma unroll
        for (int t = 0; t < 4; ++t) s += acc[t][r] * acc[t][r];
        tot[r] = s;
    }
    #pragma unroll
    for (int d2 = 1; d2 < 16; d2 <<= 1) {
        #pragma unroll
        for (int r = 0; r < 4; ++r) tot[r] += __shfl_xor(tot[r], d2);
    }
    float tm[4], rs[4];
    #pragma unroll
    for (int r = 0; r < 4; ++r) {
        float h0 = __shfl(acc[0][r], lane & 48);
        tm[r] = es / (1.f + expf(-h0)) + 1.1f;
        float sq = fmaxf(tot[r] - h0 * h0, EPS);
        rs[r] = sqrtf((tm[r] * tm[r] - 1.f) / sq);
    }
    #pragma unroll
    for (int t = 0; t < 4; ++t) {
        #pragma unroll
        for (int r = 0; r < 4; ++r) {
            int row = node0 + grp * 4 + r;
            if (row < n) {
                int j = t * 16 + col;
                float v = (j == 0) ? tm[r] : acc[t][r] * rs[r];
                out[(size_t)row * 64 + j] = f2bf_rn(v);
            }
        }
    }
}

// ================= kernels =================

// F1: embed and bcount blocks INTERLEAVED (Bresenham) for true overlap.
__global__ __launch_bounds__(256) void k_f1(const float* __restrict__ x,
                                            float* __restrict__ P,
                                            const int* __restrict__ dst,
                                            int* __restrict__ bcnt,
                                            int n, int e, int nbuck,
                                            int gEm, int gB) {
    int bid = blockIdx.x;
    int total = gEm + gB;
    int a = (int)(((long long)bid * gB) / total);
    int b = (int)(((long long)(bid + 1) * gB) / total);
    if (b > a) bcount_body(a, dst, bcnt, e, nbuck);
    else       embed_body(bid - a, x, P, n);
}

// scan bucket counts -> bstart[0..nbuck], gcur copy, off[n]=e
__global__ __launch_bounds__(512) void k_bscan(const int* __restrict__ bcnt,
                                               int* __restrict__ bstart,
                                               int* __restrict__ gcur,
                                               int* __restrict__ off,
                                               int n, int e, int nbuck) {
    __shared__ int sm[512];
    int tid = threadIdx.x;
    int v = (tid < nbuck) ? bcnt[tid] : 0;
    sm[tid] = v;
    __syncthreads();
    #pragma unroll
    for (int d = 1; d < 512; d <<= 1) {
        int t = (tid >= d) ? sm[tid - d] : 0;
        __syncthreads();
        sm[tid] += t;
        __syncthreads();
    }
    int excl = sm[tid] - v;
    if (tid < nbuck) { bstart[tid] = excl; gcur[tid] = excl; }
    if (tid == 0) { bstart[nbuck] = e; off[n] = e; }
}

// F2: bucketA (blocks [0,nA)) || lin1 (blocks [nA, nA+gL))
__global__ __launch_bounds__(256) void k_f2(const int* __restrict__ src,
                                            const int* __restrict__ dst,
                                            const float* __restrict__ wE,
                                            int* __restrict__ gcur,
                                            ull* __restrict__ tmp,
                                            int e, int nbuck, int nA,
                                            const float* __restrict__ P,
                                            const float* __restrict__ W1,
                                            const float* __restrict__ b1,
                                            const float* __restrict__ s1,
                                            unsigned short* __restrict__ T, int n) {
    if ((int)blockIdx.x < nA) bucketA_body(blockIdx.x, src, dst, wE, gcur, tmp, e, nbuck);
    else                      lin_body<0>(blockIdx.x - nA, P, W1, b1, s1, T, n);
}

// Pass B: per bucket: LDS node-hist + scan -> off, then scatter
__global__ __launch_bounds__(1024) void k_bucketB(const ull* __restrict__ tmp,
                                                  const int* __restrict__ bstart,
                                                  int* __restrict__ off,
                                                  ull* __restrict__ epack,
                                                  int n) {
    __shared__ int cur[BNODES];
    __shared__ int sm[BNODES];
    int b = blockIdx.x;
    int v0 = b << BSH;
    int nv = min(BNODES, n - v0);
    int tid = threadIdx.x;
    if (tid < BNODES) cur[tid] = 0;
    __syncthreads();
    int s0 = bstart[b], s1 = bstart[b + 1];
    for (int i = s0 + tid; i < s1; i += 1024)
        atomicAdd(&cur[((unsigned)tmp[i] >> 20) & (BNODES - 1)], 1);
    __syncthreads();
    int v = 0;
    if (tid < BNODES) { v = cur[tid]; sm[tid] = v; }
    __syncthreads();
    #pragma unroll
    for (int d = 1; d < BNODES; d <<= 1) {
        int t = 0;
        if (tid < BNODES && tid >= d) t = sm[tid - d];
        __syncthreads();
        if (tid < BNODES) sm[tid] += t;
        __syncthreads();
    }
    if (tid < BNODES) {
        int node_off = s0 + sm[tid] - v;
        if (tid < nv) off[v0 + tid] = node_off;
        cur[tid] = node_off;
    }
    __syncthreads();
    for (int i = s0 + tid; i < s1; i += 1024) {
        ull pk = tmp[i];
        int dl = ((unsigned)pk >> 20) & (BNODES - 1);
        int pos = atomicAdd(&cur[dl], 1);
        epack[pos] = pk;                        // normal store: L2 assembles lines
    }
}

__global__ __launch_bounds__(256) void k_lin2(const float* __restrict__ h1,
                                              const float* __restrict__ W2,
                                              const float* __restrict__ b2,
                                              const float* __restrict__ s2,
                                              unsigned short* __restrict__ T, int n) {
    lin_body<1>(blockIdx.x, h1, W2, b2, s2, T, n);
}

// ---------------- Aggregation: chunk-batched gathers, quarter-wave/edge -----
template <int FINAL>
__global__ __launch_bounds__(256) void k_agg(const unsigned short* __restrict__ t,
                                             const int* __restrict__ off,
                                             const ull* __restrict__ epack,
                                             const float* __restrict__ h1,
                                             float* __restrict__ out, int n) {
    __shared__ __align__(16) ull ebuf[4][64];
    int lane = threadIdx.x & 63, wv = threadIdx.x >> 6;
    int q = lane >> 4, sub = lane & 15;
    int node = blockIdx.x * 4 + wv;
    if (node >= n) return;
    int s0 = off[node], s1 = off[node + 1];
    float ax = 0.f, ay = 0.f, az = 0.f, aw = 0.f;
    for (int base = s0; base < s1; base += 64) {
        int c = min(s1 - base, 64);
        ull ev = 0;
        if (lane < c) ev = __builtin_nontemporal_load(&epack[base + lane]);
        ebuf[wv][lane] = ev;                 // same-wave LDS ordering
        int ng = (c + 3) >> 2;               // wave-uniform
        uint2 rv[16]; float wgt[16];
        #pragma unroll
        for (int g = 0; g < 16; ++g) {
            if (g < ng) {
                ull e = ebuf[wv][g * 4 + q];
                wgt[g] = __uint_as_float((unsigned)(e >> 32));
                unsigned srcn = (unsigned)e & 0xFFFFFu;
                rv[g] = *(const uint2*)((const unsigned*)(t + ((size_t)srcn << 6)) + sub * 2);
            }
        }
        #pragma unroll
        for (int g = 0; g < 16; ++g) {
            if (g < ng) {
                float w = wgt[g];
                ax += w * __uint_as_float(rv[g].x << 16);
                ay += w * __uint_as_float(rv[g].x & 0xFFFF0000u);
                az += w * __uint_as_float(rv[g].y << 16);
                aw += w * __uint_as_float(rv[g].y & 0xFFFF0000u);
            }
        }
    }
    #pragma unroll
    for (int d2 = 16; d2 <= 32; d2 <<= 1) {
        ax += __shfl_xor(ax, d2);
        ay += __shfl_xor(ay, d2);
        az += __shfl_xor(az, d2);
        aw += __shfl_xor(aw, d2);
    }
    float s = ay * ay + az * az + aw * aw;
    s += (sub == 0) ? -ax * ax : ax * ax;
    #pragma unroll
    for (int d2 = 1; d2 < 16; d2 <<= 1) s += __shfl_xor(s, d2);
    float inv = 1.f / sqrtf(fmaxf(fabsf(s), EPS));
    float hx = ax * inv, hy = ay * inv, hz = az * inv, hw = aw * inv;
    if (FINAL) {
        f32x4 hv = __builtin_nontemporal_load(
            (const f32x4*)(h1 + (size_t)node * 64 + sub * 4));
        float vx = hv[0] + hx, vy = hv[1] + hy, vz = hv[2] + hz, vw = hv[3] + hw;
        float s2 = vy * vy + vz * vz + vw * vw;
        s2 += (sub == 0) ? -vx * vx : vx * vx;
        #pragma unroll
        for (int d2 = 1; d2 < 16; d2 <<= 1) s2 += __shfl_xor(s2, d2);
        float inv2 = 1.f / sqrtf(fmaxf(fabsf(s2), EPS));
        if (lane < 16) {
            float4 r = make_float4(vx * inv2, vy * inv2, vz * inv2, vw * inv2);
            *(float4*)(out + (size_t)node * 64 + sub * 4) = r;
        }
    } else {
        if (lane < 16) {
            float4 r = make_float4(hx, hy, hz, hw);
            *(float4*)(out + (size_t)node * 64 + sub * 4) = r;
        }
    }
}

extern "C" void kernel_launch(void* const* d_in, const int* in_sizes, int n_in,
                              void* d_out, int out_size, void* d_ws, size_t ws_size,
                              hipStream_t stream) {
    const float* x  = (const float*)d_in[0];
    const int*   ei = (const int*)d_in[1];
    const float* wE = (const float*)d_in[2];
    const float* W1 = (const float*)d_in[3];
    const float* b1 = (const float*)d_in[4];
    const float* s1 = (const float*)d_in[5];
    const float* W2 = (const float*)d_in[6];
    const float* b2 = (const float*)d_in[7];
    const float* s2 = (const float*)d_in[8];
    float* out = (float*)d_out;

    const int N = in_sizes[0] / (D - 1);
    const int E = in_sizes[2];
    const int* src = ei;
    const int* dst = ei + E;
    const int nbuck = (N + BNODES - 1) >> BSH;         // 313

    // DISTINCT regions: T | B2 (f32 P/h1) | epack | tmp | ints
    char* ws = (char*)d_ws;
    unsigned short* T = (unsigned short*)ws;                       // N*D*2
    float* B2 = (float*)(ws + (((size_t)N * D * 2 + 255) & ~(size_t)255));
    ull* epack = (ull*)((char*)B2 + (size_t)N * D * 4);            // E*8
    ull* tmp   = epack + E;                                        // E*8
    int* off    = (int*)(tmp + E);                                 // N+1
    int* bcnt   = off + (N + 1);                                   // 320
    int* bstart = bcnt + 320;                                      // 320
    int* gcur   = bstart + 320;                                    // 512

    hipMemsetAsync(bcnt, 0, 320 * sizeof(int), stream);

    int gE4 = (E + 1023) / 1024;                       // 1250
    int gEm = (N + 15) / 16;                           // 5000
    int nA  = (E + ABLK - 1) / ABLK;                   // 157
    int gL  = (N + 63) / 64;                           // 1250
    int gA  = (N + 3) / 4;

    k_f1<<<gEm + gE4, 256, 0, stream>>>(x, B2, dst, bcnt, N, E, nbuck, gEm, gE4);
    k_bscan<<<1, 512, 0, stream>>>(bcnt, bstart, gcur, off, N, E, nbuck);
    k_f2<<<nA + gL, 256, 0, stream>>>(src, dst, wE, gcur, tmp, E, nbuck, nA,
                                      B2, W1, b1, s1, T, N);
    k_bucketB<<<nbuck, 1024, 0, stream>>>(tmp, bstart, off, epack, N);

    k_agg<0><<<gA, 256, 0, stream>>>(T, off, epack, nullptr, B2, N);  // h1 (f32)
    k_lin2<<<gL, 256, 0, stream>>>(B2, W2, b2, s2, T, N);             // relu(h1) -> t2
    k_agg<1><<<gA, 256, 0, stream>>>(T, off, epack, B2, out, N);
}